// Round 3
// baseline (276.390 us; speedup 1.0000x reference)
//
#include <hip/hip_runtime.h>

typedef unsigned short u16;
typedef __attribute__((ext_vector_type(8))) short short8;
typedef __attribute__((ext_vector_type(4))) float f32x4;

// ---------------- helpers ----------------

__device__ __forceinline__ u16 f2bf(float f) {
    unsigned u = __float_as_uint(f);
    u += 0x7fffu + ((u >> 16) & 1u);   // round-to-nearest-even
    return (u16)(u >> 16);
}

// async global->LDS 16B copy; per-lane dst == wave-uniform base + lane*16.
__device__ __forceinline__ void lds_cp16(const u16* g, u16* l) {
#if defined(__has_builtin) && __has_builtin(__builtin_amdgcn_global_load_lds)
    __builtin_amdgcn_global_load_lds(
        (const __attribute__((address_space(1))) void*)g,
        (__attribute__((address_space(3))) void*)l, 16, 0, 0);
#else
    *(uint4*)l = *(const uint4*)g;
#endif
}

// ---------------- shared GEMM core (projections) ----------------
// C[128x128] += A[128xK] * B^T, A row-major [row][k] (lda), Bt row-major [col][k] (ldb).
// 256 threads = 4 waves, each wave owns a 64x64 quadrant as 4x4 16x16 frags.
__device__ __forceinline__ void gemm_core(const u16* __restrict__ Ag, int lda,
                                          const u16* __restrict__ Bg, int ldb,
                                          int ksteps, u16* Alds, u16* Blds,
                                          f32x4 (&acc)[4][4]) {
    const int t = threadIdx.x;
    const int lane = t & 63;
    const int w = t >> 6;
    const int wr = (w >> 1) * 64;
    const int wc = (w & 1) * 64;
    const short8* A8 = (const short8*)Alds;
    const short8* B8 = (const short8*)Blds;

    for (int kt = 0; kt < ksteps; ++kt) {
        __syncthreads();
#pragma unroll
        for (int p = 0; p < 2; ++p) {
            const int el = w * 512 + lane * 8 + p * 2048;  // element in 128x32 tile
            const int row = el >> 5, col = el & 31;
            lds_cp16(Ag + (size_t)row * lda + kt * 32 + col, Alds + el);
            lds_cp16(Bg + (size_t)row * ldb + kt * 32 + col, Blds + el);
        }
        __syncthreads();

        short8 a[4], b[4];
#pragma unroll
        for (int i = 0; i < 4; ++i)
            a[i] = A8[(wr + i * 16 + (lane & 15)) * 4 + (lane >> 4)];
#pragma unroll
        for (int j = 0; j < 4; ++j)
            b[j] = B8[(wc + j * 16 + (lane & 15)) * 4 + (lane >> 4)];
#pragma unroll
        for (int i = 0; i < 4; ++i)
#pragma unroll
            for (int j = 0; j < 4; ++j)
                acc[i][j] = __builtin_amdgcn_mfma_f32_16x16x32_bf16(a[i], b[j], acc[i][j], 0, 0, 0);
    }
}

// ---------------- kernels ----------------

__global__ void k_cvt_x(const float4* __restrict__ X, ushort4* __restrict__ Xb, int n4) {
    for (int i = blockIdx.x * blockDim.x + threadIdx.x; i < n4; i += gridDim.x * blockDim.x) {
        float4 v = X[i];
        ushort4 o;
        o.x = f2bf(v.x); o.y = f2bf(v.y); o.z = f2bf(v.z); o.w = f2bf(v.w);
        Xb[i] = o;
    }
}

// W[k][n] fp32 -> Wt[z][n][k] bf16; z=0 (Wq) folded with 1/sqrt(2048)
__global__ void k_cvt_w(const float* __restrict__ Wq, const float* __restrict__ Wk,
                        const float* __restrict__ Wv, u16* __restrict__ Wt) {
    int idx = blockIdx.x * 256 + threadIdx.x;  // 3*512*512 total
    int z = idx >> 18;
    int nk = idx & 262143;
    int n = nk >> 9, k = nk & 511;
    const float* W = (z == 0) ? Wq : (z == 1 ? Wk : Wv);
    float v = W[k * 512 + n];
    if (z == 0) v *= 0.022097086912079608f;  // 1/sqrt(2048)
    Wt[idx] = f2bf(v);
}

// projections: z=0 -> Q(scaled), z=1 -> K, z=2 -> V stored transposed [b][d][s]
__global__ __launch_bounds__(256, 2) void k_proj(const u16* __restrict__ Xb, const u16* __restrict__ Wt,
                                                 u16* __restrict__ Qb, u16* __restrict__ Kb,
                                                 u16* __restrict__ Vt) {
    __shared__ alignas(16) u16 Alds[4096];
    __shared__ alignas(16) u16 Blds[4096];
    const int nt = blockIdx.x, mt = blockIdx.y, z = blockIdx.z;
    const u16* Ag = Xb + (size_t)mt * 128 * 512;
    const u16* Bg = Wt + (size_t)z * 512 * 512 + (size_t)nt * 128 * 512;
    f32x4 acc[4][4] = {};
    gemm_core(Ag, 512, Bg, 512, 16, Alds, Blds, acc);

    const int t = threadIdx.x, lane = t & 63, w = t >> 6;
    const int wr = (w >> 1) * 64, wc = (w & 1) * 64;
    if (z < 2) {
        u16* O = (z == 0) ? Qb : Kb;
#pragma unroll
        for (int i = 0; i < 4; ++i)
#pragma unroll
            for (int j = 0; j < 4; ++j)
#pragma unroll
                for (int r = 0; r < 4; ++r) {
                    int m = mt * 128 + wr + i * 16 + 4 * (lane >> 4) + r;
                    int n = nt * 128 + wc + j * 16 + (lane & 15);
                    O[(size_t)m * 512 + n] = f2bf(acc[i][j][r]);
                }
    } else {
        int b = mt >> 4;
#pragma unroll
        for (int i = 0; i < 4; ++i)
#pragma unroll
            for (int j = 0; j < 4; ++j) {
                int s0 = (mt * 128 + wr + i * 16 + 4 * (lane >> 4)) & 2047;
                int d = nt * 128 + wc + j * 16 + (lane & 15);
                ushort4 pk;
                pk.x = f2bf(acc[i][j][0]); pk.y = f2bf(acc[i][j][1]);
                pk.z = f2bf(acc[i][j][2]); pk.w = f2bf(acc[i][j][3]);
                *(ushort4*)(Vt + (size_t)b * 512 * 2048 + (size_t)d * 2048 + s0) = pk;
            }
    }
}

// ---------------- fused attention: scores + softmax + PV ----------------
// 512 blocks x 256 thr (4 waves). Block -> (bz = bid&7 for XCD/L2 affinity,
// q-tile qs via balanced pairing: CU c gets tiles (63-u) and (u), 65 steps total).
// Per kv-step (32 rows): QK^T from registers(Q) x global(K), exp+mask -> P in
// LDS (2KB dbuf, XOR-swizzled, ONE barrier/step), PV from LDS(P) x global(V).
// Rowsum via ones-MFMA; divide in epilogue. No P round-trip through HBM.
__global__ __launch_bounds__(256, 2) void k_attn(const u16* __restrict__ Qb, const u16* __restrict__ Kb,
                                                 const u16* __restrict__ Vt, float* __restrict__ Out) {
    __shared__ alignas(16) u16 Plds[2][2048];  // [dbuf][32q x 32kv] swizzled
    const int bid = blockIdx.x;
    const int bz = bid & 7;
    const int u = bid >> 3;                    // 0..63
    const int qs = (u < 32) ? (63 - u) : (u - 32);  // q-tile index; rows [qs*32, qs*32+32)
    const int t = threadIdx.x, lane = t & 63, w = t >> 6;
    const int g = lane >> 4, l = lane & 15;
    const int qb = w >> 1, kb = w & 1;         // QK^T role: S-frag (16q x 16kv)

    const u16* Qg = Qb + (size_t)bz * 2048 * 512 + (size_t)(qs * 32 + 16 * qb + l) * 512 + g * 8;
    const u16* Kg = Kb + (size_t)bz * 2048 * 512 + (size_t)(16 * kb + l) * 512 + g * 8;
    const u16* Vg = Vt + (size_t)bz * 512 * 2048 + (size_t)(128 * w + l) * 2048 + g * 8;

    // Q tile in registers: 16 x bf16x8 = 64 VGPR
    short8 q[16];
#pragma unroll
    for (int c = 0; c < 16; ++c) q[c] = *(const short8*)(Qg + 32 * c);

    const short ob = (short)0x3f80;
    const short8 ones = {ob, ob, ob, ob, ob, ob, ob, ob};
    f32x4 accO[2][8] = {};   // O[qf 16 rows][d-slice 128] per wave
    f32x4 accL[2] = {};      // rowsums
    const int qglob0 = qs * 32 + 16 * qb + 4 * g;  // q rows of this lane's S frag

    for (int s = 0; s <= qs; ++s) {
        // ---- QK^T: S-frag (qb,kb), K direct from global (L2) ----
        f32x4 s0 = {}, s1 = {};
        const u16* Kp = Kg + (size_t)s * 32 * 512;
#pragma unroll
        for (int c = 0; c < 8; ++c) {
            s0 = __builtin_amdgcn_mfma_f32_16x16x32_bf16(q[2 * c], *(const short8*)(Kp + 64 * c), s0, 0, 0, 0);
            s1 = __builtin_amdgcn_mfma_f32_16x16x32_bf16(q[2 * c + 1], *(const short8*)(Kp + 64 * c + 32), s1, 0, 0, 0);
        }
        // ---- mask + exp -> P (bf16) into swizzled LDS ----
        u16* Pb = &Plds[s & 1][0];
        const int kvloc = 16 * kb + l;
        const int kvglob = 32 * s + kvloc;
#pragma unroll
        for (int r = 0; r < 4; ++r) {
            const int qloc = 16 * qb + 4 * g + r;
            float sv = s0[r] + s1[r];
            float pv = (kvglob <= qglob0 + r) ? __expf(sv) : 0.0f;
            const int byte = qloc * 64 + ((((kvloc >> 3) ^ ((qloc >> 1) & 3)) << 4) | ((kvloc & 7) << 1));
            *(u16*)((char*)Pb + byte) = f2bf(pv);
        }
        __syncthreads();  // the only barrier per step (dbuf makes write(s+2) safe)
        // ---- PV: P from LDS, V direct from global (L2); wave owns d-slice 128*w ----
        short8 a[2];
#pragma unroll
        for (int qf = 0; qf < 2; ++qf) {
            const int row = 16 * qf + l;
            a[qf] = *(const short8*)((char*)Pb + row * 64 + ((g ^ ((row >> 1) & 3)) << 4));
        }
#pragma unroll
        for (int qf = 0; qf < 2; ++qf)
            accL[qf] = __builtin_amdgcn_mfma_f32_16x16x32_bf16(a[qf], ones, accL[qf], 0, 0, 0);
        const u16* Vp = Vg + (size_t)s * 32;
#pragma unroll
        for (int df = 0; df < 8; ++df) {
            const short8 vf = *(const short8*)(Vp + (size_t)df * 16 * 2048);
#pragma unroll
            for (int qf = 0; qf < 2; ++qf)
                accO[qf][df] = __builtin_amdgcn_mfma_f32_16x16x32_bf16(a[qf], vf, accO[qf][df], 0, 0, 0);
        }
    }

    // ---- epilogue: divide by rowsum, store fp32 ----
    float* Ob = Out + (size_t)bz * 2048 * 512;
#pragma unroll
    for (int qf = 0; qf < 2; ++qf) {
        float inv[4];
#pragma unroll
        for (int r = 0; r < 4; ++r) inv[r] = 1.0f / accL[qf][r];
#pragma unroll
        for (int df = 0; df < 8; ++df) {
            const int d = 128 * w + 16 * df + l;
#pragma unroll
            for (int r = 0; r < 4; ++r) {
                const int qq = qs * 32 + 16 * qf + 4 * g + r;
                Ob[(size_t)qq * 512 + d] = accO[qf][df][r] * inv[r];
            }
        }
    }
}

// ---------------- launch ----------------

extern "C" void kernel_launch(void* const* d_in, const int* in_sizes, int n_in,
                              void* d_out, int out_size, void* d_ws, size_t ws_size,
                              hipStream_t stream) {
    const float* data = (const float*)d_in[0];
    const float* Wq = (const float*)d_in[1];
    const float* Wk = (const float*)d_in[2];
    const float* Wv = (const float*)d_in[3];
    float* out = (float*)d_out;
    char* ws = (char*)d_ws;

    // workspace layout (bytes)
    u16* Xb = (u16*)(ws);                 // 16 MB  [16384][512] bf16 data
    u16* Qb = (u16*)(ws + 16777216);      // 16 MB  Q (scale folded in Wq)
    u16* Kb = (u16*)(ws + 33554432);      // 16 MB  K
    u16* Vt = (u16*)(ws + 50331648);      // 16 MB  V^T [b][d][s]
    u16* Wt = (u16*)(ws + 67108864);      // 1.5 MB [3][n][k] bf16 W^T

    k_cvt_x<<<2048, 256, 0, stream>>>((const float4*)data, (ushort4*)Xb, (8 * 2048 * 512) / 4);
    k_cvt_w<<<3072, 256, 0, stream>>>(Wq, Wk, Wv, Wt);
    k_proj<<<dim3(4, 128, 3), 256, 0, stream>>>(Xb, Wt, Qb, Kb, Vt);
    k_attn<<<512, 256, 0, stream>>>(Qb, Kb, Vt, out);
}

// Round 4
// 130.956 us; speedup vs baseline: 2.1106x; 2.1106x over previous
//
#include <hip/hip_runtime.h>

typedef unsigned short u16;
typedef __attribute__((ext_vector_type(8))) short short8;
typedef __attribute__((ext_vector_type(4))) float f32x4;

// ---------------- helpers ----------------

__device__ __forceinline__ u16 f2bf(float f) {
    unsigned u = __float_as_uint(f);
    u += 0x7fffu + ((u >> 16) & 1u);   // round-to-nearest-even
    return (u16)(u >> 16);
}

// async global->LDS 16B copy; per-lane dst == wave-uniform base + lane*16.
__device__ __forceinline__ void lds_cp16(const u16* g, u16* l) {
#if defined(__has_builtin) && __has_builtin(__builtin_amdgcn_global_load_lds)
    __builtin_amdgcn_global_load_lds(
        (const __attribute__((address_space(1))) void*)g,
        (__attribute__((address_space(3))) void*)l, 16, 0, 0);
#else
    *(uint4*)l = *(const uint4*)g;
#endif
}

// ---------------- shared GEMM core ----------------
// C[128x128] += A[128xK] * B^T, A row-major [row][k] (lda), Bt row-major [col][k] (ldb).
// 256 threads = 4 waves, each wave owns a 64x64 quadrant as 4x4 16x16 frags.
// BK=32 per K-step. Both frags loaded as contiguous bf16x8 (k-permutation cancels).
template <bool ROWSUM>
__device__ __forceinline__ void gemm_core(const u16* __restrict__ Ag, int lda,
                                          const u16* __restrict__ Bg, int ldb,
                                          int ksteps, u16* Alds, u16* Blds,
                                          f32x4 (&acc)[4][4], f32x4* accL) {
    const int t = threadIdx.x;
    const int lane = t & 63;
    const int w = t >> 6;
    const int wr = (w >> 1) * 64;
    const int wc = (w & 1) * 64;
    const short8* A8 = (const short8*)Alds;
    const short8* B8 = (const short8*)Blds;
    const short ob = (short)0x3f80;  // bf16 1.0
    const short8 ones = {ob, ob, ob, ob, ob, ob, ob, ob};

    for (int kt = 0; kt < ksteps; ++kt) {
        __syncthreads();  // previous compute done before overwrite
#pragma unroll
        for (int p = 0; p < 2; ++p) {
            const int el = w * 512 + lane * 8 + p * 2048;  // element in 128x32 tile
            const int row = el >> 5, col = el & 31;
            lds_cp16(Ag + (size_t)row * lda + kt * 32 + col, Alds + el);
            lds_cp16(Bg + (size_t)row * ldb + kt * 32 + col, Blds + el);
        }
        __syncthreads();  // vmcnt(0) drained by compiler before barrier

        short8 a[4], b[4];
#pragma unroll
        for (int i = 0; i < 4; ++i)
            a[i] = A8[(wr + i * 16 + (lane & 15)) * 4 + (lane >> 4)];
#pragma unroll
        for (int j = 0; j < 4; ++j)
            b[j] = B8[(wc + j * 16 + (lane & 15)) * 4 + (lane >> 4)];
#pragma unroll
        for (int i = 0; i < 4; ++i)
#pragma unroll
            for (int j = 0; j < 4; ++j)
                acc[i][j] = __builtin_amdgcn_mfma_f32_16x16x32_bf16(a[i], b[j], acc[i][j], 0, 0, 0);
        if constexpr (ROWSUM) {
#pragma unroll
            for (int i = 0; i < 4; ++i)
                accL[i] = __builtin_amdgcn_mfma_f32_16x16x32_bf16(a[i], ones, accL[i], 0, 0, 0);
        }
    }
}

// ---------------- kernels ----------------

// data fp32 -> bf16 (vectorized)
__global__ void k_cvt_x(const float4* __restrict__ X, ushort4* __restrict__ Xb, int n4) {
    for (int i = blockIdx.x * blockDim.x + threadIdx.x; i < n4; i += gridDim.x * blockDim.x) {
        float4 v = X[i];
        ushort4 o;
        o.x = f2bf(v.x); o.y = f2bf(v.y); o.z = f2bf(v.z); o.w = f2bf(v.w);
        Xb[i] = o;
    }
}

// W[k][n] fp32 -> Wt[z][n][k] bf16; z=0 (Wq) folded with 1/sqrt(2048)
__global__ void k_cvt_w(const float* __restrict__ Wq, const float* __restrict__ Wk,
                        const float* __restrict__ Wv, u16* __restrict__ Wt) {
    int idx = blockIdx.x * 256 + threadIdx.x;  // 3*512*512 total
    int z = idx >> 18;
    int nk = idx & 262143;
    int n = nk >> 9, k = nk & 511;
    const float* W = (z == 0) ? Wq : (z == 1 ? Wk : Wv);
    float v = W[k * 512 + n];
    if (z == 0) v *= 0.022097086912079608f;  // 1/sqrt(2048)
    Wt[idx] = f2bf(v);
}

// projections: z=0 -> Q(scaled), z=1 -> K, z=2 -> V stored transposed [b][d][s]
// Linear grid, XCD-chunked: XCD x owns mt in [x*16, x*16+16) -> X panels (2MB) L2-resident.
__global__ __launch_bounds__(256, 2) void k_proj(const u16* __restrict__ Xb, const u16* __restrict__ Wt,
                                                 u16* __restrict__ Qb, u16* __restrict__ Kb,
                                                 u16* __restrict__ Vt) {
    __shared__ alignas(16) u16 Alds[4096];
    __shared__ alignas(16) u16 Blds[4096];
    const int bid = blockIdx.x;            // 1536 blocks
    const int u = bid >> 3;                // 0..191
    const int z = u >> 6;                  // 0..2
    const int nt = (u >> 4) & 3;           // 0..3
    const int mt = (bid & 7) * 16 + (u & 15);  // 0..127, XCD-chunked
    const u16* Ag = Xb + (size_t)mt * 128 * 512;
    const u16* Bg = Wt + (size_t)z * 512 * 512 + (size_t)nt * 128 * 512;
    f32x4 acc[4][4] = {};
    gemm_core<false>(Ag, 512, Bg, 512, 16, Alds, Blds, acc, (f32x4*)nullptr);

    const int t = threadIdx.x, lane = t & 63, w = t >> 6;
    const int wr = (w >> 1) * 64, wc = (w & 1) * 64;
    if (z < 2) {
        u16* O = (z == 0) ? Qb : Kb;
#pragma unroll
        for (int i = 0; i < 4; ++i)
#pragma unroll
            for (int j = 0; j < 4; ++j)
#pragma unroll
                for (int r = 0; r < 4; ++r) {
                    int m = mt * 128 + wr + i * 16 + 4 * (lane >> 4) + r;
                    int n = nt * 128 + wc + j * 16 + (lane & 15);
                    O[(size_t)m * 512 + n] = f2bf(acc[i][j][r]);
                }
    } else {
        int b = mt >> 4;  // 2048/128 = 16 m-tiles per batch
#pragma unroll
        for (int i = 0; i < 4; ++i)
#pragma unroll
            for (int j = 0; j < 4; ++j) {
                int s0 = (mt * 128 + wr + i * 16 + 4 * (lane >> 4)) & 2047;
                int d = nt * 128 + wc + j * 16 + (lane & 15);
                ushort4 pk;
                pk.x = f2bf(acc[i][j][0]); pk.y = f2bf(acc[i][j][1]);
                pk.z = f2bf(acc[i][j][2]); pk.w = f2bf(acc[i][j][3]);
                *(ushort4*)(Vt + (size_t)b * 512 * 2048 + (size_t)d * 2048 + s0) = pk;
            }
    }
}

// scores: P[b][q][kv] = exp(q.k/sqrt(S)) masked causal, unnormalized, bf16
// Compact triangular grid: 1088 = 8 bz x 136 causal tiles; bz = bid&7 (XCD/L2 affinity).
__global__ __launch_bounds__(256, 2) void k_scores(const u16* __restrict__ Qb, const u16* __restrict__ Kb,
                                                   u16* __restrict__ P) {
    const int bid = blockIdx.x;
    const int bz = bid & 7;
    const int tt = bid >> 3;  // 0..135
    int qi = (int)((sqrtf(8.0f * tt + 1.0f) - 1.0f) * 0.5f);
    while ((qi + 1) * (qi + 2) / 2 <= tt) ++qi;
    while (qi * (qi + 1) / 2 > tt) --qi;
    const int kvj = tt - qi * (qi + 1) / 2;  // 0..qi

    __shared__ alignas(16) u16 Alds[4096];
    __shared__ alignas(16) u16 Blds[4096];
    const u16* Ag = Qb + (size_t)bz * 2048 * 512 + (size_t)qi * 128 * 512;
    const u16* Bg = Kb + (size_t)bz * 2048 * 512 + (size_t)kvj * 128 * 512;
    f32x4 acc[4][4] = {};
    gemm_core<false>(Ag, 512, Bg, 512, 16, Alds, Blds, acc, (f32x4*)nullptr);

    const int t = threadIdx.x, lane = t & 63, w = t >> 6;
    const int wr = (w >> 1) * 64, wc = (w & 1) * 64;
    u16* Pb = P + (size_t)bz * 2048 * 2048;
#pragma unroll
    for (int i = 0; i < 4; ++i)
#pragma unroll
        for (int j = 0; j < 4; ++j)
#pragma unroll
            for (int r = 0; r < 4; ++r) {
                int q = qi * 128 + wr + i * 16 + 4 * (lane >> 4) + r;
                int kv = kvj * 128 + wc + j * 16 + (lane & 15);
                float pv = (kv <= q) ? __expf(acc[i][j][r]) : 0.0f;
                Pb[(size_t)q * 2048 + kv] = f2bf(pv);
            }
}

// PV: out[b][q][d] = (sum_kv P*Vt) / rowsum(P); rowsum via ones-MFMA.
// Linear grid 512: bz = bid&7 (XCD: P[bz] panels + Vt[bz] 2MB in that XCD's L2).
// Within XCD: consecutive block pairs = (qi=qpair, qi=15-qpair) same nt ->
// per-CU work is a constant 17 k-tiles; 4 nt blocks of one qi co-resident -> P read ~once.
__global__ __launch_bounds__(256, 2) void k_pv(const u16* __restrict__ P, const u16* __restrict__ Vt,
                                               float* __restrict__ Out) {
    __shared__ alignas(16) u16 Alds[4096];
    __shared__ alignas(16) u16 Blds[4096];
    const int bid = blockIdx.x;
    const int bz = bid & 7;
    const int u = bid >> 3;        // 0..63
    const int h = u & 1;
    const int j2 = u >> 1;         // 0..31
    const int qpair = j2 >> 2;     // 0..7
    const int nt = j2 & 3;         // 0..3
    const int qi = h ? (15 - qpair) : qpair;

    const u16* Ag = P + (size_t)bz * 2048 * 2048 + (size_t)qi * 128 * 2048;
    const u16* Bg = Vt + (size_t)bz * 512 * 2048 + (size_t)nt * 128 * 2048;
    f32x4 acc[4][4] = {};
    f32x4 accL[4] = {};
    gemm_core<true>(Ag, 2048, Bg, 2048, (qi + 1) * 4, Alds, Blds, acc, accL);

    const int t = threadIdx.x, lane = t & 63, w = t >> 6;
    const int wr = (w >> 1) * 64, wc = (w & 1) * 64;
#pragma unroll
    for (int i = 0; i < 4; ++i) {
        float inv[4];
#pragma unroll
        for (int r = 0; r < 4; ++r) inv[r] = 1.0f / accL[i][r];
#pragma unroll
        for (int j = 0; j < 4; ++j) {
            int d = nt * 128 + wc + j * 16 + (lane & 15);
#pragma unroll
            for (int r = 0; r < 4; ++r) {
                int q = qi * 128 + wr + i * 16 + 4 * (lane >> 4) + r;
                Out[(size_t)bz * 2048 * 512 + (size_t)q * 512 + d] = acc[i][j][r] * inv[r];
            }
        }
    }
}

// ---------------- launch ----------------

extern "C" void kernel_launch(void* const* d_in, const int* in_sizes, int n_in,
                              void* d_out, int out_size, void* d_ws, size_t ws_size,
                              hipStream_t stream) {
    const float* data = (const float*)d_in[0];
    const float* Wq = (const float*)d_in[1];
    const float* Wk = (const float*)d_in[2];
    const float* Wv = (const float*)d_in[3];
    float* out = (float*)d_out;
    char* ws = (char*)d_ws;

    // workspace layout (bytes)
    u16* Xb = (u16*)(ws);                 // 16 MB  [16384][512] bf16 data
    u16* Qb = (u16*)(ws + 16777216);      // 16 MB  Q (scale folded in Wq)
    u16* Kb = (u16*)(ws + 33554432);      // 16 MB  K
    u16* Vt = (u16*)(ws + 50331648);      // 16 MB  V^T [b][d][s]
    u16* Wt = (u16*)(ws + 67108864);      // 1.5 MB [3][n][k] bf16 W^T
    u16* P  = (u16*)(ws + 68681728);      // 64 MB  [b][q][kv] bf16 exp(scores)

    k_cvt_x<<<2048, 256, 0, stream>>>((const float4*)data, (ushort4*)Xb, (8 * 2048 * 512) / 4);
    k_cvt_w<<<3072, 256, 0, stream>>>(Wq, Wk, Wv, Wt);
    k_proj<<<1536, 256, 0, stream>>>(Xb, Wt, Qb, Kb, Vt);
    k_scores<<<1088, 256, 0, stream>>>(Qb, Kb, P);
    k_pv<<<512, 256, 0, stream>>>(P, Vt, out);
}